// Round 24
// baseline (1798.356 us; speedup 1.0000x reference)
//
#include <hip/hip_runtime.h>
#include <hip/hip_bf16.h>

constexpr int NROW = 8192;
constexpr int INF  = 256;
constexpr int OUTF = 128;
constexpr int KSPLIT = 8;
constexpr int KCHUNK = NROW / KSPLIT; // 1024
constexpr int NIT    = KCHUNK / 64;   // 16 k-iterations per kpv block
#define LOG2E 1.4426950408889634f

typedef __bf16 bf16x8 __attribute__((ext_vector_type(8)));
typedef float  f32x4  __attribute__((ext_vector_type(4)));
typedef int    i32x4  __attribute__((ext_vector_type(4)));
typedef unsigned long long u64;

// global -> LDS direct async copy, 16 B per lane (linear dest, swizzled src).
#define GLOAD_LDS16(gsrc, ldst)                                           \
  __builtin_amdgcn_global_load_lds(                                       \
      (const __attribute__((address_space(1))) unsigned int*)(gsrc),      \
      (__attribute__((address_space(3))) unsigned int*)(ldst), 16, 0, 0)

// ---------------------------------------------------------------------------
// k1: h = x@W; f1/f2 (pre-scaled by log2e); ht = h^T bf16; zeroes out0 slice
// and this block's 16 row-flags (producer-consumer flags for k3f).
// grid: NROW/16 = 512 blocks, 256 threads
// ---------------------------------------------------------------------------
__global__ __launch_bounds__(256) void k1(const float* __restrict__ x,
                                          const float* __restrict__ W,
                                          const float* __restrict__ a,
                                          __bf16* __restrict__ ht,
                                          float* __restrict__ f1,
                                          float* __restrict__ f2,
                                          float* __restrict__ out0,
                                          unsigned* __restrict__ flag) {
  __shared__ float xs[16][INF];   // 16 KB
  __shared__ float hs[16][OUTF];  // 8 KB
  const int t  = threadIdx.x;
  const int i0 = blockIdx.x * 16;

  {
    f32x4 z = (f32x4){0.f, 0.f, 0.f, 0.f};
    f32x4* od = reinterpret_cast<f32x4*>(out0 + (size_t)i0 * OUTF);
    od[t]       = z;
    od[t + 256] = z;
    if (t < 16) flag[i0 + t] = 0u;
  }

  const f32x4* xsrc = reinterpret_cast<const f32x4*>(x + (size_t)i0 * INF);
  f32x4* xdst = reinterpret_cast<f32x4*>(&xs[0][0]);
  #pragma unroll
  for (int u = 0; u < (16 * INF / 4) / 256; ++u)
    xdst[u * 256 + t] = xsrc[u * 256 + t];
  __syncthreads();

  const int c  = t & 127;
  const int rg = t >> 7;
  float acc[8];
  #pragma unroll
  for (int r = 0; r < 8; ++r) acc[r] = 0.f;
  for (int k = 0; k < INF; ++k) {
    float wv = W[k * OUTF + c];
    #pragma unroll
    for (int r = 0; r < 8; ++r) acc[r] += xs[rg * 8 + r][k] * wv;
  }
  #pragma unroll
  for (int r = 0; r < 8; ++r) hs[rg * 8 + r][c] = acc[r];
  __syncthreads();

  const int wv = t >> 6, lane = t & 63;
  for (int r = wv; r < 16; r += 4) {
    float h0 = hs[r][lane * 2], h1 = hs[r][lane * 2 + 1];
    float s1 = h0 * a[lane * 2] + h1 * a[lane * 2 + 1];
    float s2 = h0 * a[OUTF + lane * 2] + h1 * a[OUTF + lane * 2 + 1];
    #pragma unroll
    for (int off = 32; off; off >>= 1) {
      s1 += __shfl_down(s1, off);
      s2 += __shfl_down(s2, off);
    }
    if (lane == 0) { f1[i0 + r] = s1 * LOG2E; f2[i0 + r] = s2 * LOG2E; }
  }

  const int col = t >> 1, seg = t & 1;
  bf16x8 v0;
  #pragma unroll
  for (int r = 0; r < 8; ++r) v0[r] = (__bf16)hs[seg * 8 + r][col];
  *reinterpret_cast<bf16x8*>(ht + (size_t)col * NROW + i0 + seg * 8) = v0;
}

// ---------------------------------------------------------------------------
// k3f v3: one heterogeneous kernel.
//  bid < 8192  -> WRITER block (old katt2): read adj row (NT) -> mask + s ->
//                 RELEASE flag[i] -> pure register-fed att write stream.
//  bid >= 8192 -> KPV block (r23 single-buffered path): ACQUIRE-spin on its
//                 64 row flags, then mask/s via device-coherent atomic loads.
// Deadlock-free: 5 blocks/CU (29184 B arena) = 1280 slots > 1024 kpv blocks,
// so >=256 slots always hold writers (which depend on nothing) -> progress
// under any dispatch order. kpv blocks last in grid so in-order dispatch
// makes spinning rare; writers release flags BEFORE their att-write phase,
// unblocking kpv ~50 us early.
// grid: 9216 blocks, 256 threads
// ---------------------------------------------------------------------------
__global__ __launch_bounds__(256, 5) void k3f(const int* __restrict__ adj,
                                              const __bf16* __restrict__ ht,
                                              const float* __restrict__ f1,
                                              const float* __restrict__ f2,
                                              float* __restrict__ s,
                                              u64* __restrict__ mask,
                                              unsigned* __restrict__ flag,
                                              float* __restrict__ out0,
                                              float* __restrict__ att) {
  __shared__ alignas(16) char smem[29184];  // 16K bs + 4K f2s + 8.5K ms
  const int bid = blockIdx.x;
  const int t   = threadIdx.x;

  if (bid < NROW) {
    // ========================= WRITER path ==========================
    const int i = bid;
    const int lane = t & 63, wv = t >> 6;
    const float f1i = f1[i];
    const i32x4* arow = reinterpret_cast<const i32x4*>(adj + (size_t)i * NROW);
    const f32x4* f2v  = reinterpret_cast<const f32x4*>(f2);
    u64* mrow = mask + (size_t)i * 128;
    float* red = reinterpret_cast<float*>(smem);

    // phase 1: pure read stream (f2 kept in registers)
    unsigned mynibs = 0;
    float acc = 0.f;
    f32x4 fv[8];
    #pragma unroll
    for (int it = 0; it < 8; ++it) {
      i32x4 av = __builtin_nontemporal_load(arow + it * 256 + t);
      fv[it] = f2v[it * 256 + t];
      unsigned nib = (av[0] > 0) | ((av[1] > 0) << 1) | ((av[2] > 0) << 2) |
                     ((av[3] > 0) << 3);
      mynibs |= nib << (it * 4);
      #pragma unroll
      for (int b = 0; b < 4; ++b) {
        float e = f1i + fv[it][b];
        e = e > 0.f ? e : 0.01f * e;
        acc += ((nib >> b) & 1u) ? __builtin_exp2f(e) : 0.f;
      }
    }

    // phase 1.5: mask emission + row sum
    #pragma unroll
    for (int it = 0; it < 8; ++it) {
      u64 m = (u64)((mynibs >> (it * 4)) & 0xFu) << (4 * (lane & 15));
      #pragma unroll
      for (int d = 1; d < 16; d <<= 1) m |= __shfl_xor(m, d);
      if ((lane & 15) == 0) mrow[it * 16 + (t >> 4)] = m;
    }
    #pragma unroll
    for (int off = 32; off; off >>= 1) acc += __shfl_down(acc, off);
    if (lane == 0) red[wv] = acc;
    __syncthreads();
    const float srow = red[0] + red[1] + red[2] + red[3];
    if (t == 0) s[i] = srow;
    const float inv_s = 1.0f / srow;

    // RELEASE: all threads fence their mask stores, then t0 sets the flag.
    __threadfence();
    __syncthreads();
    if (t == 0) atomicExch(&flag[i], 1u);

    // phase 2: pure write stream (no loads between stores)
    f32x4* adst = reinterpret_cast<f32x4*>(att + (size_t)i * NROW);
    #pragma unroll
    for (int it = 0; it < 8; ++it) {
      const unsigned nib = (mynibs >> (it * 4)) & 0xFu;
      f32x4 o;
      #pragma unroll
      for (int b = 0; b < 4; ++b) {
        float e = f1i + fv[it][b];
        e = e > 0.f ? e : 0.01f * e;
        o[b] = ((nib >> b) & 1u) ? __builtin_exp2f(e) * inv_s : 0.f;
      }
      adst[it * 256 + t] = o;
    }
    return;
  }

  // ========================== KPV path ============================
  __bf16* bs = reinterpret_cast<__bf16*>(smem);               // 16 KB single
  float* f2s = reinterpret_cast<float*>(smem + 16384);        // 4 KB
  u64 (*ms)[17] = reinterpret_cast<u64(*)[17]>(smem + 20480); // 8.5 KB

  const int q  = bid - NROW;
  const int mb = q / KSPLIT;
  const int ks = q % KSPLIT;
  const int w    = t >> 6;
  const int lane = t & 63;
  const int lr = lane & 15;
  const int lc = lane >> 4;
  const int row0 = mb * 64;
  const int j0 = ks * KCHUNK;

  // ACQUIRE: wait for this block's 64 producer rows.
  if (t < 64) {
    while (atomicAdd(&flag[row0 + t], 0u) == 0u)
      __builtin_amdgcn_s_sleep(16);
  }
  __syncthreads();
  __threadfence();

  const int srow = w * 32 + (lane >> 3);                    // + qq*8
  const int sgcol = ((lane & 7) ^ ((lane >> 3) & 7)) << 3;  // content swizzle
  const __bf16* sgbase = ht + (size_t)srow * NROW + j0 + sgcol;
  const int ldsu = w * 2048;  // wave base in bf16 elements

  // prologue: f2 chunk (plain: k1 output) + mask chunk (coherent atomics)
  reinterpret_cast<f32x4*>(f2s)[t] =
      reinterpret_cast<const f32x4*>(f2 + j0)[t];
  {
    const int rr = t >> 2, qq = (t & 3) * 4;
    u64* msrc = mask + (size_t)(row0 + rr) * 128 + (j0 >> 6) + qq;
    ms[rr][qq]     = atomicAdd(&msrc[0], 0ull);
    ms[rr][qq + 1] = atomicAdd(&msrc[1], 0ull);
    ms[rr][qq + 2] = atomicAdd(&msrc[2], 0ull);
    ms[rr][qq + 3] = atomicAdd(&msrc[3], 0ull);
  }
  __syncthreads();

  const int   rloc = w * 16 + lr;
  const float f1r  = f1[row0 + rloc];
  const int   s0 = (lc ^ (lr & 7)) << 3;         // swizzled read offsets
  const int   s1 = ((lc + 4) ^ (lr & 7)) << 3;

  f32x4 acc[8];
  #pragma unroll
  for (int n = 0; n < 8; ++n) acc[n] = (f32x4){0.f, 0.f, 0.f, 0.f};

  for (int it = 0; it < NIT; ++it) {
    const int kk = it * 64;

    if (it) __syncthreads();  // all waves done reading the previous tile

    #pragma unroll
    for (int qq = 0; qq < 4; ++qq)
      GLOAD_LDS16(sgbase + (size_t)(qq * 8) * NROW + kk,
                  &bs[ldsu + qq * 512]);

    const u64 mw = ms[rloc][it];
    bf16x8 afrag[2];
    #pragma unroll
    for (int h = 0; h < 2; ++h) {
      const unsigned bits = (unsigned)(mw >> (h * 32 + lc * 8)) & 0xFFu;
      const int base = kk + h * 32 + lc * 8;
      #pragma unroll
      for (int i2 = 0; i2 < 8; ++i2) {
        float e = f1r + f2s[base + i2];
        e = e > 0.f ? e : 0.01f * e;
        afrag[h][i2] = (__bf16)(((bits >> i2) & 1u) ? __builtin_exp2f(e) : 0.f);
      }
    }

    __syncthreads();  // drains vmcnt -> tile it landed in bs

    #pragma unroll
    for (int n = 0; n < 8; ++n) {
      const int rb = (n * 16 + lr) * 64;
      bf16x8 b0 = *reinterpret_cast<const bf16x8*>(&bs[rb + s0]);
      bf16x8 b1 = *reinterpret_cast<const bf16x8*>(&bs[rb + s1]);
      acc[n] = __builtin_amdgcn_mfma_f32_16x16x32_bf16(afrag[0], b0, acc[n], 0, 0, 0);
      acc[n] = __builtin_amdgcn_mfma_f32_16x16x32_bf16(afrag[1], b1, acc[n], 0, 0, 0);
    }
  }

  // epilogue: scale by 1/s (coherent atomic read), atomic accumulate
  float inv_sD[4];
  #pragma unroll
  for (int i2 = 0; i2 < 4; ++i2)
    inv_sD[i2] = 1.0f / atomicAdd(&s[row0 + w * 16 + lc * 4 + i2], 0.0f);
  #pragma unroll
  for (int n = 0; n < 8; ++n) {
    #pragma unroll
    for (int i2 = 0; i2 < 4; ++i2) {
      atomicAdd(&out0[(size_t)(row0 + w * 16 + lc * 4 + i2) * OUTF + n * 16 + lr],
                acc[n][i2] * inv_sD[i2]);
    }
  }
}

// ---------------------------------------------------------------------------
extern "C" void kernel_launch(void* const* d_in, const int* in_sizes, int n_in,
                              void* d_out, int out_size, void* d_ws, size_t ws_size,
                              hipStream_t stream) {
  const float* x   = (const float*)d_in[0];
  const int*   adj = (const int*)d_in[1];
  const float* W   = (const float*)d_in[2];
  const float* a   = (const float*)d_in[3];

  float* out0 = (float*)d_out;                       // 8192 x 128
  float* att  = (float*)d_out + (size_t)NROW * OUTF; // 8192 x 8192

  char* ws = (char*)d_ws;
  __bf16* ht = (__bf16*)ws;                                         // 2 MB
  u64* mask = (u64*)(ws + (2 << 20));                               // 8 MB
  float* f1 = (float*)(ws + (10 << 20));
  float* f2 = (float*)(ws + (10 << 20) + 32 * 1024);
  float* s  = (float*)(ws + (10 << 20) + 64 * 1024);
  unsigned* flag = (unsigned*)(ws + (10 << 20) + 96 * 1024);        // 32 KB

  k1<<<NROW / 16, 256, 0, stream>>>(x, W, a, ht, f1, f2, out0, flag);
  k3f<<<NROW + (NROW / 64) * KSPLIT, 256, 0, stream>>>(
      adj, ht, f1, f2, s, mask, flag, out0, att);
}

// Round 25
// 164.181 us; speedup vs baseline: 10.9535x; 10.9535x over previous
//
#include <hip/hip_runtime.h>
#include <hip/hip_bf16.h>

constexpr int NROW = 8192;
constexpr int INF  = 256;
constexpr int OUTF = 128;
constexpr int KSPLIT = 8;
constexpr int KCHUNK = NROW / KSPLIT; // 1024
constexpr int NIT    = KCHUNK / 64;   // 16 k-iterations per kpv block
#define LOG2E 1.4426950408889634f

typedef __bf16 bf16x8 __attribute__((ext_vector_type(8)));
typedef float  f32x4  __attribute__((ext_vector_type(4)));
typedef int    i32x4  __attribute__((ext_vector_type(4)));
typedef unsigned long long u64;

// global -> LDS direct async copy, 16 B per lane. Dest is wave-uniform base
// + lane*16 (linear); per-lane GLOBAL address carries the swizzle (m173).
#define GLOAD_LDS16(gsrc, ldst)                                           \
  __builtin_amdgcn_global_load_lds(                                       \
      (const __attribute__((address_space(1))) unsigned int*)(gsrc),      \
      (__attribute__((address_space(3))) unsigned int*)(ldst), 16, 0, 0)

// ---------------------------------------------------------------------------
// k1: h = x@W; f1/f2 (pre-scaled by log2e); ht = h^T bf16; zeroes out0 slice.
// grid: NROW/16 = 512 blocks, 256 threads
// ---------------------------------------------------------------------------
__global__ __launch_bounds__(256) void k1(const float* __restrict__ x,
                                          const float* __restrict__ W,
                                          const float* __restrict__ a,
                                          __bf16* __restrict__ ht,
                                          float* __restrict__ f1,
                                          float* __restrict__ f2,
                                          float* __restrict__ out0) {
  __shared__ float xs[16][INF];   // 16 KB
  __shared__ float hs[16][OUTF];  // 8 KB
  const int t  = threadIdx.x;
  const int i0 = blockIdx.x * 16;

  {
    f32x4 z = (f32x4){0.f, 0.f, 0.f, 0.f};
    f32x4* od = reinterpret_cast<f32x4*>(out0 + (size_t)i0 * OUTF);
    od[t]       = z;
    od[t + 256] = z;
  }

  const f32x4* xsrc = reinterpret_cast<const f32x4*>(x + (size_t)i0 * INF);
  f32x4* xdst = reinterpret_cast<f32x4*>(&xs[0][0]);
  #pragma unroll
  for (int u = 0; u < (16 * INF / 4) / 256; ++u)
    xdst[u * 256 + t] = xsrc[u * 256 + t];
  __syncthreads();

  const int c  = t & 127;
  const int rg = t >> 7;
  float acc[8];
  #pragma unroll
  for (int r = 0; r < 8; ++r) acc[r] = 0.f;
  for (int k = 0; k < INF; ++k) {
    float wv = W[k * OUTF + c];
    #pragma unroll
    for (int r = 0; r < 8; ++r) acc[r] += xs[rg * 8 + r][k] * wv;
  }
  #pragma unroll
  for (int r = 0; r < 8; ++r) hs[rg * 8 + r][c] = acc[r];
  __syncthreads();

  const int wv = t >> 6, lane = t & 63;
  for (int r = wv; r < 16; r += 4) {
    float h0 = hs[r][lane * 2], h1 = hs[r][lane * 2 + 1];
    float s1 = h0 * a[lane * 2] + h1 * a[lane * 2 + 1];
    float s2 = h0 * a[OUTF + lane * 2] + h1 * a[OUTF + lane * 2 + 1];
    #pragma unroll
    for (int off = 32; off; off >>= 1) {
      s1 += __shfl_down(s1, off);
      s2 += __shfl_down(s2, off);
    }
    if (lane == 0) { f1[i0 + r] = s1 * LOG2E; f2[i0 + r] = s2 * LOG2E; }
  }

  const int col = t >> 1, seg = t & 1;
  bf16x8 v0;
  #pragma unroll
  for (int r = 0; r < 8; ++r) v0[r] = (__bf16)hs[seg * 8 + r][col];
  *reinterpret_cast<bf16x8*>(ht + (size_t)col * NROW + i0 + seg * 8) = v0;
}

// ---------------------------------------------------------------------------
// k2: adj -> packed bitmask + row sums ONLY (att write moved to k3f so it
// overlaps PV). One wave per row, 512 cols/iter, NT int4 loads.
// grid: NROW/4 blocks, 256 threads
// ---------------------------------------------------------------------------
__global__ __launch_bounds__(256) void k2(const int* __restrict__ adj,
                                          const float* __restrict__ f1,
                                          const float* __restrict__ f2,
                                          u64* __restrict__ mask,
                                          float* __restrict__ s) {
  const int row  = blockIdx.x * 4 + (threadIdx.x >> 6);
  const int lane = threadIdx.x & 63;
  const float f1i = f1[row];
  const i32x4* arow = reinterpret_cast<const i32x4*>(adj + (size_t)row * NROW);
  const f32x4* f2v  = reinterpret_cast<const f32x4*>(f2);

  float acc = 0.f;
  for (int it = 0; it < NROW / 512; ++it) {
    i32x4 av0 = __builtin_nontemporal_load(arow + it * 128 + lane);
    i32x4 av1 = __builtin_nontemporal_load(arow + it * 128 + 64 + lane);
    f32x4 fv0 = f2v[it * 128 + lane];
    f32x4 fv1 = f2v[it * 128 + 64 + lane];

    unsigned nib0 = (av0[0] > 0) | ((av0[1] > 0) << 1) | ((av0[2] > 0) << 2) |
                    ((av0[3] > 0) << 3);
    unsigned nib1 = (av1[0] > 0) | ((av1[1] > 0) << 1) | ((av1[2] > 0) << 2) |
                    ((av1[3] > 0) << 3);
    #pragma unroll
    for (int b = 0; b < 4; ++b) {
      float e0 = f1i + fv0[b];
      e0 = e0 > 0.f ? e0 : 0.01f * e0;
      acc += ((nib0 >> b) & 1u) ? __builtin_exp2f(e0) : 0.f;
      float e1 = f1i + fv1[b];
      e1 = e1 > 0.f ? e1 : 0.01f * e1;
      acc += ((nib1 >> b) & 1u) ? __builtin_exp2f(e1) : 0.f;
    }
    u64 m0 = (u64)nib0 << (4 * (lane & 15));
    u64 m1 = (u64)nib1 << (4 * (lane & 15));
    #pragma unroll
    for (int d = 1; d < 16; d <<= 1) {
      m0 |= __shfl_xor(m0, d);
      m1 |= __shfl_xor(m1, d);
    }
    if ((lane & 15) == 0) {
      mask[(size_t)row * 128 + it * 8 + (lane >> 4)]     = m0;
      mask[(size_t)row * 128 + it * 8 + 4 + (lane >> 4)] = m1;
    }
  }
  #pragma unroll
  for (int off = 32; off; off >>= 1) acc += __shfl_down(acc, off);
  if (lane == 0) s[row] = acc;
}

// ---------------------------------------------------------------------------
// k3f v2 (r23 best configuration): heterogeneous fusion, launch-boundary
// sync only. LDS arena 28.5 KB -> 5 blocks/CU, so att-writer blocks (HBM
// store-bound) keep concurrency while kpv blocks (MFMA/VALU/LDS-bound) run
// on the same CUs; kpv's exposed single-buffer staging latency is covered
// by writer blocks. bid%9==0 -> kpv block bid/9 (1024); else att-writer row.
// grid: 9216 blocks, 256 threads
// ---------------------------------------------------------------------------
__global__ __launch_bounds__(256, 5) void k3f(const __bf16* __restrict__ ht,
                                              const float* __restrict__ f1,
                                              const float* __restrict__ f2,
                                              const float* __restrict__ sum,
                                              const u64* __restrict__ mask,
                                              float* __restrict__ out0,
                                              float* __restrict__ att) {
  __shared__ alignas(16) char smem[29184];  // 16K bs + 4K f2s + 8.5K ms
  const int bid = blockIdx.x;
  const int q  = bid / 9;
  const int r9 = bid % 9;
  const int t  = threadIdx.x;

  if (r9 != 0) {
    // ================= att-writer path: row q*8 + (r9-1) =================
    const int row = q * 8 + (r9 - 1);
    u64* msl = reinterpret_cast<u64*>(smem);  // 1 KB
    if (t < 128) msl[t] = mask[(size_t)row * 128 + t];
    const float f1i   = f1[row];
    const float inv_s = 1.0f / sum[row];
    const f32x4* f2v  = reinterpret_cast<const f32x4*>(f2);
    f32x4 fv[8];
    #pragma unroll
    for (int it = 0; it < 8; ++it) fv[it] = f2v[it * 256 + t];
    __syncthreads();
    unsigned mynibs = 0;
    #pragma unroll
    for (int it = 0; it < 8; ++it)
      mynibs |= ((unsigned)(msl[it * 16 + (t >> 4)] >> ((t & 15) * 4)) & 0xFu)
                << (it * 4);
    // pure write stream: zero loads between stores
    f32x4* adst = reinterpret_cast<f32x4*>(att + (size_t)row * NROW);
    #pragma unroll
    for (int it = 0; it < 8; ++it) {
      const unsigned nib = (mynibs >> (it * 4)) & 0xFu;
      f32x4 o;
      #pragma unroll
      for (int b = 0; b < 4; ++b) {
        float e = f1i + fv[it][b];
        e = e > 0.f ? e : 0.01f * e;
        o[b] = ((nib >> b) & 1u) ? __builtin_exp2f(e) * inv_s : 0.f;
      }
      adst[it * 256 + t] = o;
    }
    return;
  }

  // ======================= kpv path: block q =========================
  __bf16* bs = reinterpret_cast<__bf16*>(smem);               // 16 KB single
  float* f2s = reinterpret_cast<float*>(smem + 16384);        // 4 KB
  u64 (*ms)[17] = reinterpret_cast<u64(*)[17]>(smem + 20480); // 8.5 KB

  const int mb = q / KSPLIT;
  const int ks = q % KSPLIT;
  const int w    = t >> 6;
  const int lane = t & 63;
  const int lr = lane & 15;
  const int lc = lane >> 4;
  const int row0 = mb * 64;
  const int j0 = ks * KCHUNK;

  const int srow = w * 32 + (lane >> 3);                    // + qq*8
  const int sgcol = ((lane & 7) ^ ((lane >> 3) & 7)) << 3;  // content swizzle
  const __bf16* sgbase = ht + (size_t)srow * NROW + j0 + sgcol;
  const int ldsu = w * 2048;  // wave base in bf16 elements

  // ---- prologue: stage f2 chunk + mask chunk ----
  reinterpret_cast<f32x4*>(f2s)[t] =
      reinterpret_cast<const f32x4*>(f2 + j0)[t];
  {
    const int rr = t >> 2, qq = (t & 3) * 4;
    const u64* msrc = mask + (size_t)(row0 + rr) * 128 + (j0 >> 6) + qq;
    ms[rr][qq]     = msrc[0];
    ms[rr][qq + 1] = msrc[1];
    ms[rr][qq + 2] = msrc[2];
    ms[rr][qq + 3] = msrc[3];
  }
  __syncthreads();

  const int   rloc = w * 16 + lr;
  const float f1r  = f1[row0 + rloc];
  const int   s0 = (lc ^ (lr & 7)) << 3;         // swizzled read offsets
  const int   s1 = ((lc + 4) ^ (lr & 7)) << 3;

  f32x4 acc[8];
  #pragma unroll
  for (int n = 0; n < 8; ++n) acc[n] = (f32x4){0.f, 0.f, 0.f, 0.f};

  for (int it = 0; it < NIT; ++it) {
    const int kk = it * 64;

    if (it) __syncthreads();  // all waves done reading the previous tile

    // ---- stage tile it (async, direct to LDS) ----
    #pragma unroll
    for (int qq = 0; qq < 4; ++qq)
      GLOAD_LDS16(sgbase + (size_t)(qq * 8) * NROW + kk,
                  &bs[ldsu + qq * 512]);

    // ---- A-fragments (VALU-only; hides part of the staging latency) ----
    const u64 mw = ms[rloc][it];
    bf16x8 afrag[2];
    #pragma unroll
    for (int h = 0; h < 2; ++h) {
      const unsigned bits = (unsigned)(mw >> (h * 32 + lc * 8)) & 0xFFu;
      const int base = kk + h * 32 + lc * 8;
      #pragma unroll
      for (int i2 = 0; i2 < 8; ++i2) {
        float e = f1r + f2s[base + i2];
        e = e > 0.f ? e : 0.01f * e;
        afrag[h][i2] = (__bf16)(((bits >> i2) & 1u) ? __builtin_exp2f(e) : 0.f);
      }
    }

    __syncthreads();  // drains vmcnt -> tile it landed in bs

    #pragma unroll
    for (int n = 0; n < 8; ++n) {
      const int rb = (n * 16 + lr) * 64;
      bf16x8 b0 = *reinterpret_cast<const bf16x8*>(&bs[rb + s0]);
      bf16x8 b1 = *reinterpret_cast<const bf16x8*>(&bs[rb + s1]);
      acc[n] = __builtin_amdgcn_mfma_f32_16x16x32_bf16(afrag[0], b0, acc[n], 0, 0, 0);
      acc[n] = __builtin_amdgcn_mfma_f32_16x16x32_bf16(afrag[1], b1, acc[n], 0, 0, 0);
    }
  }

  float inv_sD[4];
  #pragma unroll
  for (int i2 = 0; i2 < 4; ++i2)
    inv_sD[i2] = 1.0f / sum[row0 + w * 16 + lc * 4 + i2];
  #pragma unroll
  for (int n = 0; n < 8; ++n) {
    #pragma unroll
    for (int i2 = 0; i2 < 4; ++i2) {
      atomicAdd(&out0[(size_t)(row0 + w * 16 + lc * 4 + i2) * OUTF + n * 16 + lr],
                acc[n][i2] * inv_sD[i2]);
    }
  }
}

// ---------------------------------------------------------------------------
extern "C" void kernel_launch(void* const* d_in, const int* in_sizes, int n_in,
                              void* d_out, int out_size, void* d_ws, size_t ws_size,
                              hipStream_t stream) {
  const float* x   = (const float*)d_in[0];
  const int*   adj = (const int*)d_in[1];
  const float* W   = (const float*)d_in[2];
  const float* a   = (const float*)d_in[3];

  float* out0 = (float*)d_out;                       // 8192 x 128
  float* att  = (float*)d_out + (size_t)NROW * OUTF; // 8192 x 8192

  char* ws = (char*)d_ws;
  __bf16* ht = (__bf16*)ws;                                         // 2 MB
  u64* mask = (u64*)(ws + (2 << 20));                               // 8 MB
  float* f1 = (float*)(ws + (10 << 20));
  float* f2 = (float*)(ws + (10 << 20) + 32 * 1024);
  float* s  = (float*)(ws + (10 << 20) + 64 * 1024);

  k1<<<NROW / 16, 256, 0, stream>>>(x, W, a, ht, f1, f2, out0);
  k2<<<NROW / 4, 256, 0, stream>>>(adj, f1, f2, mask, s);
  k3f<<<9216, 256, 0, stream>>>(ht, f1, f2, s, mask, out0, att);
}